// Round 8
// baseline (357.386 us; speedup 1.0000x reference)
//
#include <hip/hip_runtime.h>

typedef __attribute__((ext_vector_type(8))) short short8;
typedef __attribute__((ext_vector_type(4))) float floatx4;

#define T_SIZE 32768
#define OBS    256
#define H      512
#define NC     512     // scan chunks
#define CHUNK  64      // T_SIZE / NC
#define NGRP   64      // scan2 groups
#define GCH    8       // chunks per group
#define SLAB   ((size_t)T_SIZE * 32)   // one h-block slab in tiled layout

__device__ __forceinline__ unsigned short f2bf(float f){
    union { float f; unsigned u; } v; v.f = f;
    unsigned u = v.u;
    u += 0x7FFFu + ((u >> 16) & 1u);   // round-to-nearest-even
    return (unsigned short)(u >> 16);
}
__device__ __forceinline__ float bf2f(unsigned short u){
    union { unsigned u; float f; } v; v.u = ((unsigned)u) << 16; return v.f;
}

// async global->LDS, 16B per lane; lds base must be wave-uniform (HW adds lane*16)
#define GLOAD_LDS16(g, l) \
    __builtin_amdgcn_global_load_lds((const __attribute__((address_space(1))) unsigned*)(g), \
                                     (__attribute__((address_space(3))) unsigned*)(l), 16, 0, 0)

// ---- cast x [T,OBS] fp32 -> bf16, vectorized ----
__global__ void cast_x_kernel(const float* __restrict__ x, unsigned short* __restrict__ xb, int n4){
    int i = blockIdx.x * 256 + threadIdx.x;
    if (i < n4){
        float4 v = ((const float4*)x)[i];
        ushort4 o;
        o.x = f2bf(v.x); o.y = f2bf(v.y); o.z = f2bf(v.z); o.w = f2bf(v.w);
        ((ushort4*)xb)[i] = o;
    }
}

// ---- transpose+cast 4 weights W[K][512] fp32 -> interleaved [h/16][slot][16h][K] bf16 ----
__global__ void tcast4_kernel(const float* __restrict__ W0, const float* __restrict__ W1,
                              const float* __restrict__ W2, const float* __restrict__ W3,
                              unsigned short* __restrict__ dst, int K, int KH){
    int idx = blockIdx.x * 256 + threadIdx.x;
    if (idx >= 4 * KH) return;
    int s   = idx / KH;
    int rem = idx - s * KH;
    int k = rem >> 9;            // H == 512
    int h = rem & 511;
    const float* W = (s == 0) ? W0 : (s == 1) ? W1 : (s == 2) ? W2 : W3;
    int b = h >> 4, hh = h & 15;
    dst[(size_t)((b * 4 + s) * 16 + hh) * K + k] = f2bf(W[(size_t)k * H + h]);
}

// ---- fused 4-matrix GEMM: lead-2 software pipeline (3 LDS bufs, raw s_barrier +
//      s_waitcnt vmcnt(8)) + 1-phase epilogue + scan1 fused ----
// xb: [T][K] bf16.  wt: [H/16][4 slots][16 h][K] bf16 (slot: 0=in,1=B,2=C,3=d).
// Outputs TILED bf16 [H/32][T][32]: gT (=delta*-exp(A_log)), bxT, CT.  Pbuf/Hbuf [NC][H].
__global__ __launch_bounds__(256) void gemm_layer_kernel(
    const unsigned short* __restrict__ xb,
    const unsigned short* __restrict__ wt,
    const float* __restrict__ A_log,
    unsigned short* __restrict__ gT, unsigned short* __restrict__ bxT, unsigned short* __restrict__ CT,
    float* __restrict__ Pbuf, float* __restrict__ Hbuf,
    int K)
{
    // three 16 KB buffers: [buf][A(4096 shorts) | B(4096 shorts)]; epilogue reuses 32 KB
    __shared__ unsigned short SM[3][8192];

    const int tid  = threadIdx.x;
    const int wave = tid >> 6;
    const int lane = tid & 63;
    const int ml   = lane & 15;
    const int quad = lane >> 4;
    const int wm   = wave & 1;
    const int wn   = wave >> 1;

    // XCD-aware swizzle: all 16 nb-blocks of one mb land on one XCD (A-panel L2 reuse)
    const int flat = blockIdx.y * 16 + blockIdx.x;
    const int xcd  = flat & 7;
    const int j    = flat >> 3;
    const int nb   = j & 15;                 // 0..15 : h block of 32
    const int mb   = (j >> 4) * 8 + xcd;     // 0..255 : t tile of 128
    const int m0   = mb * 128;

    const int srow = tid >> 2;
    const int sel  = (((tid & 3) ^ ((tid >> 3) & 3))) * 8;   // staging XOR swizzle
    const int swz  = (ml >> 1) & 3;                          // read-side XOR swizzle

    const unsigned short* pa0 = xb + (size_t)(m0 + srow) * K + sel;
    const unsigned short* pa1 = pa0 + (size_t)64 * K;
    const unsigned short* pb0 = wt + (size_t)(nb * 128 + srow) * K + sel;
    const unsigned short* pb1 = pb0 + (size_t)64 * K;

    const int ldsA0 = (wave * 64 + 0  ) * 8;
    const int ldsA1 = (wave * 64 + 256) * 8;

    floatx4 acc[4][4];
    #pragma unroll
    for (int i = 0; i < 4; i++)
        #pragma unroll
        for (int jj = 0; jj < 4; jj++)
            acc[i][jj] = (floatx4)(0.0f);

    const int nk = K >> 5;
    // prologue: stage K-steps 0 and 1
    GLOAD_LDS16(pa0,      &SM[0][ldsA0]);
    GLOAD_LDS16(pa1,      &SM[0][ldsA1]);
    GLOAD_LDS16(pb0,      &SM[0][4096 + ldsA0]);
    GLOAD_LDS16(pb1,      &SM[0][4096 + ldsA1]);
    GLOAD_LDS16(pa0 + 32, &SM[1][ldsA0]);
    GLOAD_LDS16(pa1 + 32, &SM[1][ldsA1]);
    GLOAD_LDS16(pb0 + 32, &SM[1][4096 + ldsA0]);
    GLOAD_LDS16(pb1 + 32, &SM[1][4096 + ldsA1]);

    int rd = 0, wr = 2;
    for (int kk = 0; kk < nk; ++kk){
        // all my LDS reads of iter kk-1 have returned; rendezvous so the buffer
        // being overwritten below (read at iter kk-1) is free across the block
        asm volatile("s_waitcnt lgkmcnt(0)" ::: "memory");
        asm volatile("s_barrier" ::: "memory");

        // issue DMA for iter kk+2 (clamped tail re-fetch: L2-hot, harmless)
        const int kf = (kk + 2 < nk) ? (kk + 2) : (nk - 1);
        const int ko = kf * 32;
        GLOAD_LDS16(pa0 + ko, &SM[wr][ldsA0]);
        GLOAD_LDS16(pa1 + ko, &SM[wr][ldsA1]);
        GLOAD_LDS16(pb0 + ko, &SM[wr][4096 + ldsA0]);
        GLOAD_LDS16(pb1 + ko, &SM[wr][4096 + ldsA1]);

        // wait only for the oldest 4 loads (buffer kk); keep 8 in flight
        asm volatile("s_waitcnt vmcnt(8)" ::: "memory");

        const unsigned short* As = &SM[rd][0];
        const unsigned short* Bs = &SM[rd][4096];
        short8 av[4], bv[4];
        #pragma unroll
        for (int i = 0; i < 4; i++)
            av[i] = *(const short8*)(As + (size_t)(wm * 64 + i * 16 + ml) * 32 + (quad ^ swz) * 8);
        #pragma unroll
        for (int jj = 0; jj < 4; jj++)
            bv[jj] = *(const short8*)(Bs + (size_t)(wn * 64 + jj * 16 + ml) * 32 + (quad ^ swz) * 8);

        #pragma unroll
        for (int i = 0; i < 4; i++)
            #pragma unroll
            for (int jj = 0; jj < 4; jj++)
                acc[i][jj] = __builtin_amdgcn_mfma_f32_16x16x32_bf16(av[i], bv[jj], acc[i][jj], 0, 0, 0);

        // rotate: next read = rd+1 (mod 3); next write = current rd
        const int tmp = rd;
        rd = (rd == 2) ? 0 : rd + 1;
        wr = tmp;
    }
    // drain everything (incl. tail garbage DMAs) before reusing LDS
    asm volatile("s_waitcnt lgkmcnt(0)" ::: "memory");
    asm volatile("s_waitcnt vmcnt(0)" ::: "memory");
    __syncthreads();

    // ---- epilogue (one LDS phase): g@0, bx@4096, C@8192 shorts; segbuf @16384 ----
    unsigned short* SMe = &SM[0][0];
    float2* segbuf = (float2*)(&SM[2][0]);   // disjoint 8 KB region
    const int col = wn * 16 + ml;            // 0..31 h within block
    const int h   = nb * 32 + col;
    const float Aneg = -expf(A_log[h]);

    #pragma unroll
    for (int i = 0; i < 4; i++){
        float p = 1.0f, hh = 0.0f;
        #pragma unroll
        for (int r = 0; r < 4; r++){
            int trow = wm * 64 + i * 16 + quad * 4 + r;   // C/D: row = quad*4 + reg
            float dv = acc[i][3][r];
            float delta = 1.0f / (1.0f + expf(-dv));
            unsigned short gb = f2bf(delta * Aneg);
            float a = expf(bf2f(gb));                     // rounded -> consistent with scan3
            unsigned short bb = f2bf(acc[i][1][r] * acc[i][0][r]);
            SMe[        trow * 32 + col] = gb;
            SMe[4096 +  trow * 32 + col] = bb;
            SMe[8192 +  trow * 32 + col] = f2bf(acc[i][2][r]);
            hh = fmaf(a, hh, bf2f(bb));
            p *= a;
        }
        segbuf[(i * 4 + quad) * 64 + col * 2 + wm] = make_float2(p, hh);
    }
    __syncthreads();
    {
        const short8* s8 = (const short8*)SMe;
        short8* dg = (short8*)(gT  + (size_t)nb * SLAB + (size_t)m0 * 32);
        short8* db = (short8*)(bxT + (size_t)nb * SLAB + (size_t)m0 * 32);
        short8* dc = (short8*)(CT  + (size_t)nb * SLAB + (size_t)m0 * 32);
        dg[tid] = s8[tid];        dg[tid + 256] = s8[tid + 256];
        db[tid] = s8[512 + tid];  db[tid + 256] = s8[768 + tid];
        dc[tid] = s8[1024 + tid]; dc[tid + 256] = s8[1280 + tid];
    }
    if (tid < 64){
        int ccol = tid >> 1, ch = tid & 1;
        float P = 1.0f, Hc = 0.0f;
        #pragma unroll
        for (int s = 0; s < 16; s++){
            float2 ph = segbuf[s * 64 + ccol * 2 + ch];
            Hc = fmaf(ph.x, Hc, ph.y);
            P *= ph.x;
        }
        int c = mb * 2 + ch;
        Pbuf[(size_t)c * H + nb * 32 + ccol] = P;
        Hbuf[(size_t)c * H + nb * 32 + ccol] = Hc;
    }
}

// ---- scan pass 2a: 64 groups x 8 chunks -> group aggregates only ----
__global__ void scan2a_kernel(const float* __restrict__ P, const float* __restrict__ Hc,
                              float* __restrict__ Pg, float* __restrict__ Hg){
    const int g  = blockIdx.x;          // 0..63
    const int j4 = threadIdx.x * 4;     // 128 threads
    float4 pc = {1.f,1.f,1.f,1.f}, hc = {0.f,0.f,0.f,0.f};
    #pragma unroll
    for (int i = 0; i < GCH; i++){
        size_t o = (size_t)(g * GCH + i) * H + j4;
        float4 P4 = *(const float4*)(P + o);
        float4 H4 = *(const float4*)(Hc + o);
        hc.x = fmaf(P4.x, hc.x, H4.x); pc.x *= P4.x;
        hc.y = fmaf(P4.y, hc.y, H4.y); pc.y *= P4.y;
        hc.z = fmaf(P4.z, hc.z, H4.z); pc.z *= P4.z;
        hc.w = fmaf(P4.w, hc.w, H4.w); pc.w *= P4.w;
    }
    *(float4*)(Pg + (size_t)g * H + j4) = pc;
    *(float4*)(Hg + (size_t)g * H + j4) = hc;
}

// ---- scan pass 2b: sequential exclusive combine over 64 groups (1 block, 512 threads) ----
__global__ void scan2b_kernel(const float* __restrict__ Pg, const float* __restrict__ Hg,
                              float* __restrict__ Cg){
    const int j = threadIdx.x;
    float carry = 0.0f;
    for (int g0 = 0; g0 < NGRP; g0 += 8){
        float p[8], h[8];
        #pragma unroll
        for (int i = 0; i < 8; i++){
            p[i] = Pg[(size_t)(g0 + i) * H + j];
            h[i] = Hg[(size_t)(g0 + i) * H + j];
        }
        #pragma unroll
        for (int i = 0; i < 8; i++){
            Cg[(size_t)(g0 + i) * H + j] = carry;
            carry = fmaf(p[i], carry, h[i]);
        }
    }
}

// ---- scan pass 3: h0 = fold(group prefix) from Pbuf/Hbuf + Cg; apply; y=C*h bf16 [T][H] ----
__global__ void scan3_kernel(const unsigned short* __restrict__ gT, const unsigned short* __restrict__ bxT,
                             const unsigned short* __restrict__ CT,
                             const float* __restrict__ P, const float* __restrict__ Hc,
                             const float* __restrict__ Cg,
                             unsigned short* __restrict__ yb){
    int idx = blockIdx.x * 256 + threadIdx.x;
    int j4 = (idx & 127) * 4;
    int c  = idx >> 7;                  // wave-uniform
    int nb = j4 >> 5, jj = j4 & 31;
    int grp = c >> 3;                   // NC/GCH = 64 groups
    float4 h = *(const float4*)(Cg + (size_t)grp * H + j4);
    for (int cc = grp << 3; cc < c; ++cc){          // <=7 L2-hot folds, wave-uniform count
        float4 P4 = *(const float4*)(P + (size_t)cc * H + j4);
        float4 H4 = *(const float4*)(Hc + (size_t)cc * H + j4);
        h.x = fmaf(P4.x, h.x, H4.x);
        h.y = fmaf(P4.y, h.y, H4.y);
        h.z = fmaf(P4.z, h.z, H4.z);
        h.w = fmaf(P4.w, h.w, H4.w);
    }
    size_t off = (size_t)nb * SLAB + (size_t)c * CHUNK * 32 + jj;
    size_t yo  = (size_t)c * CHUNK * H + j4;
    #pragma unroll 8
    for (int i = 0; i < CHUNK; i++){
        ushort4 gv = *(const ushort4*)(gT + off);
        ushort4 bv = *(const ushort4*)(bxT + off);
        ushort4 cv = *(const ushort4*)(CT + off);
        h.x = fmaf(expf(bf2f(gv.x)), h.x, bf2f(bv.x));
        h.y = fmaf(expf(bf2f(gv.y)), h.y, bf2f(bv.y));
        h.z = fmaf(expf(bf2f(gv.z)), h.z, bf2f(bv.z));
        h.w = fmaf(expf(bf2f(gv.w)), h.w, bf2f(bv.w));
        ushort4 o;
        o.x = f2bf(bf2f(cv.x) * h.x);
        o.y = f2bf(bf2f(cv.y) * h.y);
        o.z = f2bf(bf2f(cv.z) * h.z);
        o.w = f2bf(bf2f(cv.w) * h.w);
        *(ushort4*)(yb + yo) = o;
        off += 32; yo += H;
    }
}

// ---- final: out[t][0:4] = y[t]@W_out + b_out + xb[t]@W_skip  (y,xb bf16; wave per row) ----
__global__ __launch_bounds__(256) void final_kernel(const unsigned short* __restrict__ y2,
                                                    const unsigned short* __restrict__ xb,
                                                    const float* __restrict__ Wout,
                                                    const float* __restrict__ bout,
                                                    const float* __restrict__ Wskip,
                                                    float* __restrict__ out){
    int wave = threadIdx.x >> 6;
    int lane = threadIdx.x & 63;
    int t = blockIdx.x * 4 + wave;
    float s0 = 0.f, s1 = 0.f, s2 = 0.f, s3 = 0.f;
    const float4* W4 = (const float4*)Wout;
    #pragma unroll
    for (int k = lane; k < H; k += 64){
        float yv = bf2f(y2[(size_t)t * H + k]);
        float4 w = W4[k];
        s0 = fmaf(yv, w.x, s0); s1 = fmaf(yv, w.y, s1);
        s2 = fmaf(yv, w.z, s2); s3 = fmaf(yv, w.w, s3);
    }
    const float4* S4 = (const float4*)Wskip;
    #pragma unroll
    for (int k = lane; k < OBS; k += 64){
        float xv = bf2f(xb[(size_t)t * OBS + k]);
        float4 w = S4[k];
        s0 = fmaf(xv, w.x, s0); s1 = fmaf(xv, w.y, s1);
        s2 = fmaf(xv, w.z, s2); s3 = fmaf(xv, w.w, s3);
    }
    #pragma unroll
    for (int off = 32; off > 0; off >>= 1){
        s0 += __shfl_down(s0, off);
        s1 += __shfl_down(s1, off);
        s2 += __shfl_down(s2, off);
        s3 += __shfl_down(s3, off);
    }
    if (lane == 0){
        out[(size_t)t * 4 + 0] = s0 + bout[0];
        out[(size_t)t * 4 + 1] = s1 + bout[1];
        out[(size_t)t * 4 + 2] = s2 + bout[2];
        out[(size_t)t * 4 + 3] = s3 + bout[3];
    }
}

extern "C" void kernel_launch(void* const* d_in, const int* in_sizes, int n_in,
                              void* d_out, int out_size, void* d_ws, size_t ws_size,
                              hipStream_t stream)
{
    const float* x     = (const float*)d_in[0];
    const float* W_in0 = (const float*)d_in[1];
    const float* W_B0  = (const float*)d_in[2];
    const float* W_C0  = (const float*)d_in[3];
    const float* W_d0  = (const float*)d_in[4];
    const float* A0    = (const float*)d_in[5];
    const float* W_in1 = (const float*)d_in[6];
    const float* W_B1  = (const float*)d_in[7];
    const float* W_C1  = (const float*)d_in[8];
    const float* W_d1  = (const float*)d_in[9];
    const float* A1    = (const float*)d_in[10];
    const float* Wout  = (const float*)d_in[11];
    const float* bout  = (const float*)d_in[12];
    const float* Wskip = (const float*)d_in[13];
    float* out = (float*)d_out;

    char* ws = (char*)d_ws;
    size_t off = 0;
    auto alloc = [&](size_t bytes) -> void* {
        void* p = ws + off;
        off += (bytes + 255) & ~(size_t)255;
        return p;
    };
    unsigned short* xb  = (unsigned short*)alloc((size_t)T_SIZE * OBS * 2);
    unsigned short* yb  = (unsigned short*)alloc((size_t)T_SIZE * H * 2);  // layer0 y; reused for layer1 y
    unsigned short* Wt0 = (unsigned short*)alloc((size_t)4 * H * OBS * 2);
    unsigned short* Wt1 = (unsigned short*)alloc((size_t)4 * H * H * 2);
    unsigned short* gT  = (unsigned short*)alloc((size_t)T_SIZE * H * 2);
    unsigned short* bxT = (unsigned short*)alloc((size_t)T_SIZE * H * 2);
    unsigned short* CT  = (unsigned short*)alloc((size_t)T_SIZE * H * 2);
    float* Pbuf = (float*)alloc((size_t)NC * H * 4);
    float* Hbuf = (float*)alloc((size_t)NC * H * 4);
    float* Pg   = (float*)alloc((size_t)NGRP * H * 4);
    float* Hg   = (float*)alloc((size_t)NGRP * H * 4);
    float* Cg   = (float*)alloc((size_t)NGRP * H * 4);
    (void)ws_size; (void)in_sizes; (void)n_in; (void)out_size;

    // ---- precision casts / weight transposes (interleaved layout) ----
    cast_x_kernel<<<(T_SIZE * OBS / 4 + 255) / 256, 256, 0, stream>>>(x, xb, T_SIZE * OBS / 4);
    tcast4_kernel<<<(4 * OBS * H + 255) / 256, 256, 0, stream>>>(W_in0, W_B0, W_C0, W_d0, Wt0, OBS, OBS * H);
    tcast4_kernel<<<(4 * H   * H + 255) / 256, 256, 0, stream>>>(W_in1, W_B1, W_C1, W_d1, Wt1, H,   H * H);

    dim3 ggrid(16, 256);                 // flat-swizzled inside the kernel
    const int sgrid = NC * 128 / 256;    // 256 blocks

    // ---- layer 0 ----
    gemm_layer_kernel<<<ggrid, 256, 0, stream>>>(xb, Wt0, A0, gT, bxT, CT, Pbuf, Hbuf, OBS);
    scan2a_kernel<<<NGRP, 128, 0, stream>>>(Pbuf, Hbuf, Pg, Hg);
    scan2b_kernel<<<1, H, 0, stream>>>(Pg, Hg, Cg);
    scan3_kernel<<<sgrid, 256, 0, stream>>>(gT, bxT, CT, Pbuf, Hbuf, Cg, yb);

    // ---- layer 1 ----
    gemm_layer_kernel<<<ggrid, 256, 0, stream>>>(yb, Wt1, A1, gT, bxT, CT, Pbuf, Hbuf, H);
    scan2a_kernel<<<NGRP, 128, 0, stream>>>(Pbuf, Hbuf, Pg, Hg);
    scan2b_kernel<<<1, H, 0, stream>>>(Pg, Hg, Cg);
    scan3_kernel<<<sgrid, 256, 0, stream>>>(gT, bxT, CT, Pbuf, Hbuf, Cg, yb /*reuse: layer1 y*/);

    // ---- output head ----
    final_kernel<<<T_SIZE / 4, 256, 0, stream>>>(yb, xb, Wout, bout, Wskip, out);
}

// Round 9
// 334.193 us; speedup vs baseline: 1.0694x; 1.0694x over previous
//
#include <hip/hip_runtime.h>

typedef __attribute__((ext_vector_type(8))) short short8;
typedef __attribute__((ext_vector_type(4))) float floatx4;

#define T_SIZE 32768
#define OBS    256
#define H      512
#define NC     1024    // scan chunks
#define CHUNK  32      // T_SIZE / NC
#define NGRP   64      // scan2 groups
#define GCH    16      // chunks per group
#define SLAB   ((size_t)T_SIZE * 32)   // one h-block slab in tiled layout

__device__ __forceinline__ unsigned short f2bf(float f){
    union { float f; unsigned u; } v; v.f = f;
    unsigned u = v.u;
    u += 0x7FFFu + ((u >> 16) & 1u);   // round-to-nearest-even
    return (unsigned short)(u >> 16);
}
__device__ __forceinline__ float bf2f(unsigned short u){
    union { unsigned u; float f; } v; v.u = ((unsigned)u) << 16; return v.f;
}

// async global->LDS, 16B per lane; lds base must be wave-uniform (HW adds lane*16)
#define GLOAD_LDS16(g, l) \
    __builtin_amdgcn_global_load_lds((const __attribute__((address_space(1))) unsigned*)(g), \
                                     (__attribute__((address_space(3))) unsigned*)(l), 16, 0, 0)

// ---- cast x [T,OBS] fp32 -> bf16, vectorized ----
__global__ void cast_x_kernel(const float* __restrict__ x, unsigned short* __restrict__ xb, int n4){
    int i = blockIdx.x * 256 + threadIdx.x;
    if (i < n4){
        float4 v = ((const float4*)x)[i];
        ushort4 o;
        o.x = f2bf(v.x); o.y = f2bf(v.y); o.z = f2bf(v.z); o.w = f2bf(v.w);
        ((ushort4*)xb)[i] = o;
    }
}

// ---- transpose+cast 4 weights W[K][512] fp32 -> interleaved [h/16][slot][16h][K] bf16 ----
__global__ void tcast4_kernel(const float* __restrict__ W0, const float* __restrict__ W1,
                              const float* __restrict__ W2, const float* __restrict__ W3,
                              unsigned short* __restrict__ dst, int K, int KH){
    int idx = blockIdx.x * 256 + threadIdx.x;
    if (idx >= 4 * KH) return;
    int s   = idx / KH;
    int rem = idx - s * KH;
    int k = rem >> 9;            // H == 512
    int h = rem & 511;
    const float* W = (s == 0) ? W0 : (s == 1) ? W1 : (s == 2) ? W2 : W3;
    int b = h >> 4, hh = h & 15;
    dst[(size_t)((b * 4 + s) * 16 + hh) * K + k] = f2bf(W[(size_t)k * H + h]);
}

// ---- fused 4-matrix GEMM (dbuf LDS, K templated + fully unrolled) + epilogue + scan1 ----
// xb: [T][K] bf16.  wt: [H/16][4 slots][16 h][K] bf16 (slot: 0=in,1=B,2=C,3=d).
// Outputs TILED bf16 [H/32][T][32]: gT (=delta*-exp(A_log)), bxT, CT.
// Chunk aggregates (CHUNK=32): 4 per block -> Pbuf/Hbuf [NC][H] fp32.
template<int K>
__global__ __launch_bounds__(256) void gemm_layer_kernel(
    const unsigned short* __restrict__ xb,
    const unsigned short* __restrict__ wt,
    const float* __restrict__ A_log,
    unsigned short* __restrict__ gT, unsigned short* __restrict__ bxT, unsigned short* __restrict__ CT,
    float* __restrict__ Pbuf, float* __restrict__ Hbuf)
{
    // two 16 KB buffers: [buf][A(4096 shorts) | B(4096 shorts)]; epilogue reuses 32 KB
    __shared__ unsigned short SM[2][8192];

    const int tid  = threadIdx.x;
    const int wave = tid >> 6;
    const int lane = tid & 63;
    const int ml   = lane & 15;
    const int quad = lane >> 4;
    const int wm   = wave & 1;
    const int wn   = wave >> 1;

    // XCD-aware swizzle: all 16 nb-blocks of one mb land on one XCD (A-panel L2 reuse)
    const int flat = blockIdx.y * 16 + blockIdx.x;
    const int xcd  = flat & 7;
    const int j    = flat >> 3;
    const int nb   = j & 15;                 // 0..15 : h block of 32
    const int mb   = (j >> 4) * 8 + xcd;     // 0..255 : t tile of 128
    const int m0   = mb * 128;

    const int srow = tid >> 2;
    const int sel  = (((tid & 3) ^ ((tid >> 3) & 3))) * 8;   // staging XOR swizzle
    const int swz  = (ml >> 1) & 3;                          // read-side XOR swizzle

    const unsigned short* pa0 = xb + (size_t)(m0 + srow) * K + sel;
    const unsigned short* pa1 = pa0 + (size_t)64 * K;
    const unsigned short* pb0 = wt + (size_t)(nb * 128 + srow) * K + sel;
    const unsigned short* pb1 = pb0 + (size_t)64 * K;

    const int ldsA0 = (wave * 64 + 0  ) * 8;
    const int ldsA1 = (wave * 64 + 256) * 8;

    // lane-dependent LDS read base (elements); everything else is a constant offset
    const int rbaseA = (wm * 64 + ml) * 32 + (quad ^ swz) * 8;
    const int rbaseB = (wn * 64 + ml) * 32 + (quad ^ swz) * 8;

    floatx4 acc[4][4];
    #pragma unroll
    for (int i = 0; i < 4; i++)
        #pragma unroll
        for (int jj = 0; jj < 4; jj++)
            acc[i][jj] = (floatx4)(0.0f);

    constexpr int NK = K >> 5;
    // prologue: stage K-step 0 into buf 0
    GLOAD_LDS16(pa0, &SM[0][ldsA0]);
    GLOAD_LDS16(pa1, &SM[0][ldsA1]);
    GLOAD_LDS16(pb0, &SM[0][4096 + ldsA0]);
    GLOAD_LDS16(pb1, &SM[0][4096 + ldsA1]);

    #pragma unroll
    for (int kk = 0; kk < NK; ++kk){
        __syncthreads();
        constexpr_if_helper:;
        const int cur = kk & 1;                  // compile-time after full unroll
        if (kk + 1 < NK){
            const int nxt = cur ^ 1;
            const int ko  = (kk + 1) * 32;       // compile-time
            GLOAD_LDS16(pa0 + ko, &SM[nxt][ldsA0]);
            GLOAD_LDS16(pa1 + ko, &SM[nxt][ldsA1]);
            GLOAD_LDS16(pb0 + ko, &SM[nxt][4096 + ldsA0]);
            GLOAD_LDS16(pb1 + ko, &SM[nxt][4096 + ldsA1]);
        }

        short8 av[4], bv[4];
        #pragma unroll
        for (int i = 0; i < 4; i++)
            av[i] = *(const short8*)(&SM[cur][0] + rbaseA + i * 16 * 32);
        #pragma unroll
        for (int jj = 0; jj < 4; jj++)
            bv[jj] = *(const short8*)(&SM[cur][4096] + rbaseB + jj * 16 * 32);

        #pragma unroll
        for (int i = 0; i < 4; i++)
            #pragma unroll
            for (int jj = 0; jj < 4; jj++)
                acc[i][jj] = __builtin_amdgcn_mfma_f32_16x16x32_bf16(av[i], bv[jj], acc[i][jj], 0, 0, 0);
    }
    __syncthreads();   // all LDS reads done before epilogue reuses SM

    // ---- epilogue (one LDS phase): g@0, bx@4096, C@8192 shorts; segbuf @24576 bytes ----
    unsigned short* SMe = &SM[0][0];
    float2* segbuf = (float2*)(SMe + 12288);  // [ch 4][seg 8][col 32] float2 = 8 KB
    const int col = wn * 16 + ml;             // 0..31 h within block
    const int h   = nb * 32 + col;
    const float Aneg = -expf(A_log[h]);

    #pragma unroll
    for (int i = 0; i < 4; i++){
        float p = 1.0f, hh = 0.0f;
        #pragma unroll
        for (int r = 0; r < 4; r++){
            int trow = wm * 64 + i * 16 + quad * 4 + r;   // C/D: row = quad*4 + reg
            float dv = acc[i][3][r];
            float delta = 1.0f / (1.0f + expf(-dv));
            unsigned short gb = f2bf(delta * Aneg);
            float a = expf(bf2f(gb));                     // rounded -> consistent with scan3
            unsigned short bb = f2bf(acc[i][1][r] * acc[i][0][r]);
            SMe[        trow * 32 + col] = gb;
            SMe[4096 +  trow * 32 + col] = bb;
            SMe[8192 +  trow * 32 + col] = f2bf(acc[i][2][r]);
            hh = fmaf(a, hh, bf2f(bb));
            p *= a;
        }
        // 4-row segment -> chunk ch (32 rows), ordered position s within chunk
        const int ch = wm * 2 + (i >> 1);
        const int s  = (i & 1) * 4 + quad;
        segbuf[(ch * 8 + s) * 32 + col] = make_float2(p, hh);
    }
    __syncthreads();
    {
        const short8* s8 = (const short8*)SMe;
        short8* dg = (short8*)(gT  + (size_t)nb * SLAB + (size_t)m0 * 32);
        short8* db = (short8*)(bxT + (size_t)nb * SLAB + (size_t)m0 * 32);
        short8* dc = (short8*)(CT  + (size_t)nb * SLAB + (size_t)m0 * 32);
        dg[tid] = s8[tid];        dg[tid + 256] = s8[tid + 256];
        db[tid] = s8[512 + tid];  db[tid + 256] = s8[768 + tid];
        dc[tid] = s8[1024 + tid]; dc[tid + 256] = s8[1280 + tid];
    }
    if (tid < 128){
        const int ccol = tid & 31, ch = tid >> 5;
        float P = 1.0f, Hc = 0.0f;
        #pragma unroll
        for (int s = 0; s < 8; s++){
            float2 ph = segbuf[(ch * 8 + s) * 32 + ccol];
            Hc = fmaf(ph.x, Hc, ph.y);
            P *= ph.x;
        }
        const int c = mb * 4 + ch;
        Pbuf[(size_t)c * H + nb * 32 + ccol] = P;
        Hbuf[(size_t)c * H + nb * 32 + ccol] = Hc;
    }
}

// ---- scan pass 2a: 64 groups x 16 chunks -> group aggregates only ----
__global__ void scan2a_kernel(const float* __restrict__ P, const float* __restrict__ Hc,
                              float* __restrict__ Pg, float* __restrict__ Hg){
    const int g  = blockIdx.x;          // 0..63
    const int j4 = threadIdx.x * 4;     // 128 threads
    float4 pc = {1.f,1.f,1.f,1.f}, hc = {0.f,0.f,0.f,0.f};
    #pragma unroll
    for (int i = 0; i < GCH; i++){
        size_t o = (size_t)(g * GCH + i) * H + j4;
        float4 P4 = *(const float4*)(P + o);
        float4 H4 = *(const float4*)(Hc + o);
        hc.x = fmaf(P4.x, hc.x, H4.x); pc.x *= P4.x;
        hc.y = fmaf(P4.y, hc.y, H4.y); pc.y *= P4.y;
        hc.z = fmaf(P4.z, hc.z, H4.z); pc.z *= P4.z;
        hc.w = fmaf(P4.w, hc.w, H4.w); pc.w *= P4.w;
    }
    *(float4*)(Pg + (size_t)g * H + j4) = pc;
    *(float4*)(Hg + (size_t)g * H + j4) = hc;
}

// ---- scan pass 2b: sequential exclusive combine over 64 groups (1 block, 512 threads) ----
__global__ void scan2b_kernel(const float* __restrict__ Pg, const float* __restrict__ Hg,
                              float* __restrict__ Cg){
    const int j = threadIdx.x;
    float carry = 0.0f;
    for (int g0 = 0; g0 < NGRP; g0 += 8){
        float p[8], h[8];
        #pragma unroll
        for (int i = 0; i < 8; i++){
            p[i] = Pg[(size_t)(g0 + i) * H + j];
            h[i] = Hg[(size_t)(g0 + i) * H + j];
        }
        #pragma unroll
        for (int i = 0; i < 8; i++){
            Cg[(size_t)(g0 + i) * H + j] = carry;
            carry = fmaf(p[i], carry, h[i]);
        }
    }
}

// ---- scan pass 3: h0 = fold(group prefix) from Pbuf/Hbuf + Cg; apply; y=C*h bf16 [T][H] ----
__global__ void scan3_kernel(const unsigned short* __restrict__ gT, const unsigned short* __restrict__ bxT,
                             const unsigned short* __restrict__ CT,
                             const float* __restrict__ P, const float* __restrict__ Hc,
                             const float* __restrict__ Cg,
                             unsigned short* __restrict__ yb){
    int idx = blockIdx.x * 256 + threadIdx.x;
    int j4 = (idx & 127) * 4;
    int c  = idx >> 7;                  // wave-uniform (0..NC-1)
    int nb = j4 >> 5, jj = j4 & 31;
    int grp = c >> 4;                   // NC/GCH = 64 groups
    float4 h = *(const float4*)(Cg + (size_t)grp * H + j4);
    for (int cc = grp << 4; cc < c; ++cc){          // <=15 L2-hot folds, wave-uniform count
        float4 P4 = *(const float4*)(P + (size_t)cc * H + j4);
        float4 H4 = *(const float4*)(Hc + (size_t)cc * H + j4);
        h.x = fmaf(P4.x, h.x, H4.x);
        h.y = fmaf(P4.y, h.y, H4.y);
        h.z = fmaf(P4.z, h.z, H4.z);
        h.w = fmaf(P4.w, h.w, H4.w);
    }
    size_t off = (size_t)nb * SLAB + (size_t)c * CHUNK * 32 + jj;
    size_t yo  = (size_t)c * CHUNK * H + j4;
    #pragma unroll 8
    for (int i = 0; i < CHUNK; i++){
        ushort4 gv = *(const ushort4*)(gT + off);
        ushort4 bv = *(const ushort4*)(bxT + off);
        ushort4 cv = *(const ushort4*)(CT + off);
        h.x = fmaf(expf(bf2f(gv.x)), h.x, bf2f(bv.x));
        h.y = fmaf(expf(bf2f(gv.y)), h.y, bf2f(bv.y));
        h.z = fmaf(expf(bf2f(gv.z)), h.z, bf2f(bv.z));
        h.w = fmaf(expf(bf2f(gv.w)), h.w, bf2f(bv.w));
        ushort4 o;
        o.x = f2bf(bf2f(cv.x) * h.x);
        o.y = f2bf(bf2f(cv.y) * h.y);
        o.z = f2bf(bf2f(cv.z) * h.z);
        o.w = f2bf(bf2f(cv.w) * h.w);
        *(ushort4*)(yb + yo) = o;
        off += 32; yo += H;
    }
}

// ---- final: out[t][0:4] = y[t]@W_out + b_out + xb[t]@W_skip  (y,xb bf16; wave per row) ----
__global__ __launch_bounds__(256) void final_kernel(const unsigned short* __restrict__ y2,
                                                    const unsigned short* __restrict__ xb,
                                                    const float* __restrict__ Wout,
                                                    const float* __restrict__ bout,
                                                    const float* __restrict__ Wskip,
                                                    float* __restrict__ out){
    int wave = threadIdx.x >> 6;
    int lane = threadIdx.x & 63;
    int t = blockIdx.x * 4 + wave;
    float s0 = 0.f, s1 = 0.f, s2 = 0.f, s3 = 0.f;
    const float4* W4 = (const float4*)Wout;
    #pragma unroll
    for (int k = lane; k < H; k += 64){
        float yv = bf2f(y2[(size_t)t * H + k]);
        float4 w = W4[k];
        s0 = fmaf(yv, w.x, s0); s1 = fmaf(yv, w.y, s1);
        s2 = fmaf(yv, w.z, s2); s3 = fmaf(yv, w.w, s3);
    }
    const float4* S4 = (const float4*)Wskip;
    #pragma unroll
    for (int k = lane; k < OBS; k += 64){
        float xv = bf2f(xb[(size_t)t * OBS + k]);
        float4 w = S4[k];
        s0 = fmaf(xv, w.x, s0); s1 = fmaf(xv, w.y, s1);
        s2 = fmaf(xv, w.z, s2); s3 = fmaf(xv, w.w, s3);
    }
    #pragma unroll
    for (int off = 32; off > 0; off >>= 1){
        s0 += __shfl_down(s0, off);
        s1 += __shfl_down(s1, off);
        s2 += __shfl_down(s2, off);
        s3 += __shfl_down(s3, off);
    }
    if (lane == 0){
        out[(size_t)t * 4 + 0] = s0 + bout[0];
        out[(size_t)t * 4 + 1] = s1 + bout[1];
        out[(size_t)t * 4 + 2] = s2 + bout[2];
        out[(size_t)t * 4 + 3] = s3 + bout[3];
    }
}

extern "C" void kernel_launch(void* const* d_in, const int* in_sizes, int n_in,
                              void* d_out, int out_size, void* d_ws, size_t ws_size,
                              hipStream_t stream)
{
    const float* x     = (const float*)d_in[0];
    const float* W_in0 = (const float*)d_in[1];
    const float* W_B0  = (const float*)d_in[2];
    const float* W_C0  = (const float*)d_in[3];
    const float* W_d0  = (const float*)d_in[4];
    const float* A0    = (const float*)d_in[5];
    const float* W_in1 = (const float*)d_in[6];
    const float* W_B1  = (const float*)d_in[7];
    const float* W_C1  = (const float*)d_in[8];
    const float* W_d1  = (const float*)d_in[9];
    const float* A1    = (const float*)d_in[10];
    const float* Wout  = (const float*)d_in[11];
    const float* bout  = (const float*)d_in[12];
    const float* Wskip = (const float*)d_in[13];
    float* out = (float*)d_out;

    char* ws = (char*)d_ws;
    size_t off = 0;
    auto alloc = [&](size_t bytes) -> void* {
        void* p = ws + off;
        off += (bytes + 255) & ~(size_t)255;
        return p;
    };
    unsigned short* xb  = (unsigned short*)alloc((size_t)T_SIZE * OBS * 2);
    unsigned short* yb  = (unsigned short*)alloc((size_t)T_SIZE * H * 2);  // layer0 y; reused for layer1 y
    unsigned short* Wt0 = (unsigned short*)alloc((size_t)4 * H * OBS * 2);
    unsigned short* Wt1 = (unsigned short*)alloc((size_t)4 * H * H * 2);
    unsigned short* gT  = (unsigned short*)alloc((size_t)T_SIZE * H * 2);
    unsigned short* bxT = (unsigned short*)alloc((size_t)T_SIZE * H * 2);
    unsigned short* CT  = (unsigned short*)alloc((size_t)T_SIZE * H * 2);
    float* Pbuf = (float*)alloc((size_t)NC * H * 4);
    float* Hbuf = (float*)alloc((size_t)NC * H * 4);
    float* Pg   = (float*)alloc((size_t)NGRP * H * 4);
    float* Hg   = (float*)alloc((size_t)NGRP * H * 4);
    float* Cg   = (float*)alloc((size_t)NGRP * H * 4);
    (void)ws_size; (void)in_sizes; (void)n_in; (void)out_size;

    // ---- precision casts / weight transposes (interleaved layout) ----
    cast_x_kernel<<<(T_SIZE * OBS / 4 + 255) / 256, 256, 0, stream>>>(x, xb, T_SIZE * OBS / 4);
    tcast4_kernel<<<(4 * OBS * H + 255) / 256, 256, 0, stream>>>(W_in0, W_B0, W_C0, W_d0, Wt0, OBS, OBS * H);
    tcast4_kernel<<<(4 * H   * H + 255) / 256, 256, 0, stream>>>(W_in1, W_B1, W_C1, W_d1, Wt1, H,   H * H);

    dim3 ggrid(16, 256);                 // flat-swizzled inside the kernel
    const int sgrid = NC * 128 / 256;    // 512 blocks

    // ---- layer 0 ----
    gemm_layer_kernel<OBS><<<ggrid, 256, 0, stream>>>(xb, Wt0, A0, gT, bxT, CT, Pbuf, Hbuf);
    scan2a_kernel<<<NGRP, 128, 0, stream>>>(Pbuf, Hbuf, Pg, Hg);
    scan2b_kernel<<<1, H, 0, stream>>>(Pg, Hg, Cg);
    scan3_kernel<<<sgrid, 256, 0, stream>>>(gT, bxT, CT, Pbuf, Hbuf, Cg, yb);

    // ---- layer 1 ----
    gemm_layer_kernel<H><<<ggrid, 256, 0, stream>>>(yb, Wt1, A1, gT, bxT, CT, Pbuf, Hbuf);
    scan2a_kernel<<<NGRP, 128, 0, stream>>>(Pbuf, Hbuf, Pg, Hg);
    scan2b_kernel<<<1, H, 0, stream>>>(Pg, Hg, Cg);
    scan3_kernel<<<sgrid, 256, 0, stream>>>(gT, bxT, CT, Pbuf, Hbuf, Cg, yb /*reuse: layer1 y*/);

    // ---- output head ----
    final_kernel<<<T_SIZE / 4, 256, 0, stream>>>(yb, xb, Wout, bout, Wskip, out);
}